// Round 4
// baseline (704.980 us; speedup 1.0000x reference)
//
#include <hip/hip_runtime.h>

// Sizes
#define Gg   128
#define N1   512
#define FH   128
#define K1   256
#define K2   128

typedef unsigned short ush;
typedef __bf16 bf16x8 __attribute__((ext_vector_type(8)));
typedef float  floatx4 __attribute__((ext_vector_type(4)));

__device__ inline float wredsum(float v) {
#pragma unroll
    for (int o = 32; o; o >>= 1) v += __shfl_xor(v, o, 64);
    return v;
}
__device__ inline float wredmax(float v) {
#pragma unroll
    for (int o = 32; o; o >>= 1) v = fmaxf(v, __shfl_xor(v, o, 64));
    return v;
}
__device__ inline ush bf_rne(float x) {
    unsigned u = __float_as_uint(x);
    return (ush)((u + 0x7fffu + ((u >> 16) & 1u)) >> 16);
}
__device__ inline float bf2f(ush u) { return __uint_as_float((unsigned)u << 16); }
// 3-way split: v ~= hi + mid + lo to ~26 mantissa bits
__device__ inline void split3(float v, ush& h, ush& m, ush& l) {
    h = bf_rne(v);
    float r1 = v - bf2f(h);
    m = bf_rne(r1);
    l = bf_rne(r1 - bf2f(m));
}

// ---------------------------------------------------------------------------
// prep: degrees + adj -> bf16 copy (exact: values are 0.0/1.0)
// ---------------------------------------------------------------------------
__global__ __launch_bounds__(256) void k_prep(const float* __restrict__ adj,
        float* __restrict__ dinv_gcn, float* __restrict__ dinv_info,
        ush* __restrict__ adjbf) {
    int wave = threadIdx.x >> 6, lane = threadIdx.x & 63;
    long long row = (long long)blockIdx.x * 4 + wave;
    const float* ar = adj + row * N1;
    ush* br = adjbf + row * N1;
    float s = 0.f;
    ush ub[8] __attribute__((aligned(16)));
#pragma unroll
    for (int c = 0; c < 2; ++c) {
        float4 v = *(const float4*)(ar + lane * 8 + c * 4);
        s += (v.x + v.y) + (v.z + v.w);
        ub[c * 4 + 0] = (ush)(__float_as_uint(v.x) >> 16);
        ub[c * 4 + 1] = (ush)(__float_as_uint(v.y) >> 16);
        ub[c * 4 + 2] = (ush)(__float_as_uint(v.z) >> 16);
        ub[c * 4 + 3] = (ush)(__float_as_uint(v.w) >> 16);
    }
    *(uint4*)(br + lane * 8) = *(const uint4*)&ub[0];
    s = wredsum(s);
    if (lane == 0) {
        dinv_gcn[row]  = rsqrtf(s + 1.0f);
        dinv_info[row] = 1.0f / fmaxf(s, 1.0f);
    }
}

// ---------------------------------------------------------------------------
// Row-weight GEMM + transposed-split epilogue:
//   C[M,128] = rs[row]*(A[M,128] @ W[128,128]);  T{h,m,l}[g][f][KD] = split(C^T)
// ---------------------------------------------------------------------------
template<int KD>
__global__ __launch_bounds__(256) void k_gemm_rwt(const float* __restrict__ A,
        const float* __restrict__ W, float* __restrict__ C,
        const float* __restrict__ rs,
        ush* __restrict__ Thi, ush* __restrict__ Tmid, ush* __restrict__ Tlo) {
    __shared__ float Al[64 * 68];
    __shared__ float Wl[64 * 132];          // reused as Cl[64][129] in epilogue
    long long row0 = (long long)blockIdx.x * 64;
    int tid = threadIdx.x, tr = tid >> 4, tc = tid & 15;
    float acc[4][8] = {};
    for (int ch = 0; ch < 2; ++ch) {
        for (int p = tid; p < 1024; p += 256) {
            int r = p >> 4, c4 = p & 15;
            *(float4*)&Al[r * 68 + c4 * 4] = *(const float4*)(A + (row0 + r) * 128 + ch * 64 + c4 * 4);
        }
        for (int p = tid; p < 2048; p += 256) {
            int r = p >> 5, c4 = p & 31;
            *(float4*)&Wl[r * 132 + c4 * 4] = *(const float4*)(W + (ch * 64 + r) * 128 + c4 * 4);
        }
        __syncthreads();
        for (int k = 0; k < 64; ++k) {
            float4 w0 = *(const float4*)&Wl[k * 132 + tc * 8];
            float4 w1 = *(const float4*)&Wl[k * 132 + tc * 8 + 4];
            float w[8] = {w0.x, w0.y, w0.z, w0.w, w1.x, w1.y, w1.z, w1.w};
#pragma unroll
            for (int i = 0; i < 4; ++i) {
                float a = Al[(tr * 4 + i) * 68 + k];
#pragma unroll
                for (int j = 0; j < 8; ++j) acc[i][j] = fmaf(a, w[j], acc[i][j]);
            }
        }
        __syncthreads();
    }
    float* Cl = Wl;                          // [64][129]
#pragma unroll
    for (int i = 0; i < 4; ++i) {
        long long r = row0 + tr * 4 + i;
        float sc = rs ? rs[r] : 1.0f;
        float v[8];
#pragma unroll
        for (int j = 0; j < 8; ++j) v[j] = sc * acc[i][j];
        *(float4*)(C + r * 128 + tc * 8)     = make_float4(v[0], v[1], v[2], v[3]);
        *(float4*)(C + r * 128 + tc * 8 + 4) = make_float4(v[4], v[5], v[6], v[7]);
#pragma unroll
        for (int j = 0; j < 8; ++j) Cl[(tr * 4 + i) * 129 + tc * 8 + j] = v[j];
    }
    __syncthreads();
    // transposed split write
    int f = tid >> 1, half = tid & 1;
    int g = (int)(row0 / KD), rk0 = (int)(row0 % KD);
    ush hb[32] __attribute__((aligned(16)));
    ush mb[32] __attribute__((aligned(16)));
    ush lb[32] __attribute__((aligned(16)));
#pragma unroll
    for (int i = 0; i < 32; ++i)
        split3(Cl[(half * 32 + i) * 129 + f], hb[i], mb[i], lb[i]);
    long long ob = ((long long)g * 128 + f) * KD + rk0 + half * 32;
#pragma unroll
    for (int q = 0; q < 4; ++q) {
        *(uint4*)(Thi  + ob + q * 8) = *(const uint4*)&hb[q * 8];
        *(uint4*)(Tmid + ob + q * 8) = *(const uint4*)&mb[q * 8];
        *(uint4*)(Tlo  + ob + q * 8) = *(const uint4*)&lb[q * 8];
    }
}

// ---------------------------------------------------------------------------
// stage-1 MFMA aggregation: C = adjbf(512x512 exact bf16) @ (Bhi+Bmid+Blo)
//  EPI 0: outH = relu(di*(C+hx)+bias), optional transposed splits of outH
//  EPI 1: outS_i = sum_n |hx - C*di|
// ---------------------------------------------------------------------------
template<int EPI, bool WRT>
__global__ __launch_bounds__(256) void k_aggmm2(const ush* __restrict__ adjbf,
        const ush* __restrict__ Bhi, const ush* __restrict__ Bmid, const ush* __restrict__ Blo,
        const float* __restrict__ dvec, const float* __restrict__ hx,
        const float* __restrict__ bias, float* __restrict__ outH, float* __restrict__ outS,
        ush* __restrict__ Thi, ush* __restrict__ Tmid, ush* __restrict__ Tlo) {
    __shared__ char smem[41984] __attribute__((aligned(16)));
    ush* Asm = (ush*)smem;                               // [128][40]
    float* sred = (float*)(smem + 40960);                // [2][128]
    float* Cl = (float*)smem;                            // epilogue alias [64][129]
    int b = blockIdx.x;                                  // 512
    int g  = (b & 7) + ((b >> 5) << 3);
    int rb = (b >> 3) & 3;
    int tid = threadIdx.x;
    int w = tid >> 6, lane = tid & 63;
    int wm = w >> 1, wn = w & 1;
    int ln = lane & 15, quad = lane >> 4;
    floatx4 acc[4][4];
#pragma unroll
    for (int i = 0; i < 4; ++i)
#pragma unroll
        for (int j = 0; j < 4; ++j) { floatx4 z = {0.f, 0.f, 0.f, 0.f}; acc[i][j] = z; }

    const long long abase = ((long long)g * 512 + rb * 128) * 512;
    const long long bbase = (long long)g * 128 * 512;
    for (int kk = 0; kk < 512; kk += 32) {
        __syncthreads();
#pragma unroll
        for (int i = 0; i < 2; ++i) {
            int id = tid + i * 256;
            int r = id >> 2, c = id & 3;
            *(uint4*)&Asm[r * 40 + c * 8] = *(const uint4*)(adjbf + abase + (long long)r * 512 + kk + c * 8);
        }
#pragma unroll
        for (int mB = 0; mB < 3; ++mB) {
            const ush* Bp = (mB == 0) ? Bhi : (mB == 1 ? Bmid : Blo);
            ush* dst = (ush*)(smem + 10240 + mB * 10240);
#pragma unroll
            for (int i = 0; i < 2; ++i) {
                int id = tid + i * 256;
                int r = id >> 2, c = id & 3;
                *(uint4*)&dst[r * 40 + c * 8] = *(const uint4*)(Bp + bbase + (long long)r * 512 + kk + c * 8);
            }
        }
        __syncthreads();
        bf16x8 af[4];
#pragma unroll
        for (int tm = 0; tm < 4; ++tm)
            af[tm] = *(const bf16x8*)&Asm[(wm * 64 + tm * 16 + ln) * 40 + quad * 8];
#pragma unroll
        for (int s = 0; s < 3; ++s) {
            const ush* Bs = (const ush*)(smem + 10240 + s * 10240);
#pragma unroll
            for (int tn = 0; tn < 4; ++tn) {
                bf16x8 bfr = *(const bf16x8*)&Bs[(wn * 64 + tn * 16 + ln) * 40 + quad * 8];
#pragma unroll
                for (int tm = 0; tm < 4; ++tm)
                    acc[tm][tn] = __builtin_amdgcn_mfma_f32_16x16x32_bf16(af[tm], bfr, acc[tm][tn], 0, 0, 0);
            }
        }
    }
    long long rowbase = (long long)g * 512 + rb * 128;
    if (EPI == 0) {
#pragma unroll
        for (int tm = 0; tm < 4; ++tm)
#pragma unroll
        for (int r = 0; r < 4; ++r) {
            long long grow = rowbase + wm * 64 + tm * 16 + quad * 4 + r;
            float di = dvec[grow];
#pragma unroll
            for (int tn = 0; tn < 4; ++tn) {
                int nc = wn * 64 + tn * 16 + ln;
                float o = fmaxf(fmaf(di, acc[tm][tn][r] + hx[grow * 128 + nc], bias[nc]), 0.f);
                outH[grow * 128 + nc] = o;
                acc[tm][tn][r] = o;
            }
        }
        if (WRT) {
#pragma unroll
            for (int p = 0; p < 2; ++p) {
                __syncthreads();
                if (wm == p) {
#pragma unroll
                    for (int tm = 0; tm < 4; ++tm)
#pragma unroll
                    for (int r = 0; r < 4; ++r)
#pragma unroll
                    for (int tn = 0; tn < 4; ++tn)
                        Cl[(tm * 16 + quad * 4 + r) * 129 + wn * 64 + tn * 16 + ln] = acc[tm][tn][r];
                }
                __syncthreads();
                int f = tid >> 1, half = tid & 1;
                ush hb[32] __attribute__((aligned(16)));
                ush mb[32] __attribute__((aligned(16)));
                ush lb[32] __attribute__((aligned(16)));
#pragma unroll
                for (int i = 0; i < 32; ++i)
                    split3(Cl[(half * 32 + i) * 129 + f], hb[i], mb[i], lb[i]);
                long long ob = ((long long)g * 128 + f) * 512 + rb * 128 + p * 64 + half * 32;
#pragma unroll
                for (int q = 0; q < 4; ++q) {
                    *(uint4*)(Thi  + ob + q * 8) = *(const uint4*)&hb[q * 8];
                    *(uint4*)(Tmid + ob + q * 8) = *(const uint4*)&mb[q * 8];
                    *(uint4*)(Tlo  + ob + q * 8) = *(const uint4*)&lb[q * 8];
                }
            }
        }
    } else {
#pragma unroll
        for (int tm = 0; tm < 4; ++tm)
#pragma unroll
        for (int r = 0; r < 4; ++r) {
            int ml = wm * 64 + tm * 16 + quad * 4 + r;
            long long grow = rowbase + ml;
            float di = dvec[grow];
            float v = 0.f;
#pragma unroll
            for (int tn = 0; tn < 4; ++tn) {
                int nc = wn * 64 + tn * 16 + ln;
                v += fabsf(hx[grow * 128 + nc] - acc[tm][tn][r] * di);
            }
            v += __shfl_xor(v, 1); v += __shfl_xor(v, 2);
            v += __shfl_xor(v, 4); v += __shfl_xor(v, 8);
            if (ln == 0) sred[wn * 128 + ml] = v;
        }
        __syncthreads();
        if (tid < 128) outS[rowbase + tid] = sred[tid] + sred[128 + tid];
    }
}

// ---------------------------------------------------------------------------
// pooled MFMA aggregation: C[i][f] = sum_j A(i,j) Y(j,f), A/Y 3-split bf16,
// 6 cross-term MFMAs (~fp32 accuracy). A row-major [g][KD][KD]; Y^T [g][128][KD].
//  EPI 0: outH = relu(di*(C+hx)+bias) (+ optional transposed splits)
//  EPI 1: outS_i = sum_f |hx - C*di|
// ---------------------------------------------------------------------------
template<int KD, int EPI, bool WRT>
__global__ __launch_bounds__(256) void k_aggp(
        const ush* __restrict__ Ahi, const ush* __restrict__ Amid, const ush* __restrict__ Alo,
        const ush* __restrict__ Yhi, const ush* __restrict__ Ymid, const ush* __restrict__ Ylo,
        const float* __restrict__ dvec, const float* __restrict__ hx,
        const float* __restrict__ bias, float* __restrict__ outH, float* __restrict__ outS,
        ush* __restrict__ Thi, ush* __restrict__ Tmid, ush* __restrict__ Tlo) {
    __shared__ char smem[62464] __attribute__((aligned(16)));
    float* sred = (float*)(smem + 61440);
    float* Cl = (float*)smem;
    int b = blockIdx.x;
    int g, rb;
    if (KD == 256) { g = (b & 7) + ((b >> 4) << 3); rb = (b >> 3) & 1; }
    else           { g = b; rb = 0; }
    int tid = threadIdx.x;
    int w = tid >> 6, lane = tid & 63;
    int wm = w >> 1, wn = w & 1;
    int ln = lane & 15, quad = lane >> 4;
    floatx4 acc[4][4];
#pragma unroll
    for (int i = 0; i < 4; ++i)
#pragma unroll
        for (int j = 0; j < 4; ++j) { floatx4 z = {0.f, 0.f, 0.f, 0.f}; acc[i][j] = z; }

    const long long abase = ((long long)g * KD + rb * 128) * KD;
    const long long ybase = (long long)g * 128 * KD;
    for (int kk = 0; kk < KD; kk += 32) {
        __syncthreads();
#pragma unroll
        for (int mP = 0; mP < 3; ++mP) {
            const ush* Ap = (mP == 0) ? Ahi : (mP == 1 ? Amid : Alo);
            const ush* Yp = (mP == 0) ? Yhi : (mP == 1 ? Ymid : Ylo);
            ush* dstA = (ush*)(smem + mP * 10240);
            ush* dstB = (ush*)(smem + 30720 + mP * 10240);
#pragma unroll
            for (int i = 0; i < 2; ++i) {
                int id = tid + i * 256;
                int r = id >> 2, c = id & 3;
                *(uint4*)&dstA[r * 40 + c * 8] = *(const uint4*)(Ap + abase + (long long)r * KD + kk + c * 8);
                *(uint4*)&dstB[r * 40 + c * 8] = *(const uint4*)(Yp + ybase + (long long)r * KD + kk + c * 8);
            }
        }
        __syncthreads();
        bf16x8 af[3][4];
#pragma unroll
        for (int mP = 0; mP < 3; ++mP) {
            const ush* As = (const ush*)(smem + mP * 10240);
#pragma unroll
            for (int tm = 0; tm < 4; ++tm)
                af[mP][tm] = *(const bf16x8*)&As[(wm * 64 + tm * 16 + ln) * 40 + quad * 8];
        }
#pragma unroll
        for (int tn = 0; tn < 4; ++tn) {
            int brow = (wn * 64 + tn * 16 + ln) * 40 + quad * 8;
            bf16x8 bh = *(const bf16x8*)&((const ush*)(smem + 30720))[brow];
            bf16x8 bm = *(const bf16x8*)&((const ush*)(smem + 40960))[brow];
            bf16x8 bl = *(const bf16x8*)&((const ush*)(smem + 51200))[brow];
#pragma unroll
            for (int tm = 0; tm < 4; ++tm) {
                acc[tm][tn] = __builtin_amdgcn_mfma_f32_16x16x32_bf16(af[0][tm], bh, acc[tm][tn], 0, 0, 0);
                acc[tm][tn] = __builtin_amdgcn_mfma_f32_16x16x32_bf16(af[0][tm], bm, acc[tm][tn], 0, 0, 0);
                acc[tm][tn] = __builtin_amdgcn_mfma_f32_16x16x32_bf16(af[1][tm], bh, acc[tm][tn], 0, 0, 0);
                acc[tm][tn] = __builtin_amdgcn_mfma_f32_16x16x32_bf16(af[0][tm], bl, acc[tm][tn], 0, 0, 0);
                acc[tm][tn] = __builtin_amdgcn_mfma_f32_16x16x32_bf16(af[1][tm], bm, acc[tm][tn], 0, 0, 0);
                acc[tm][tn] = __builtin_amdgcn_mfma_f32_16x16x32_bf16(af[2][tm], bh, acc[tm][tn], 0, 0, 0);
            }
        }
    }
    long long rowbase = (long long)g * KD + rb * 128;
    if (EPI == 0) {
#pragma unroll
        for (int tm = 0; tm < 4; ++tm)
#pragma unroll
        for (int r = 0; r < 4; ++r) {
            long long grow = rowbase + wm * 64 + tm * 16 + quad * 4 + r;
            float di = dvec[grow];
#pragma unroll
            for (int tn = 0; tn < 4; ++tn) {
                int nc = wn * 64 + tn * 16 + ln;
                float o = fmaxf(fmaf(di, acc[tm][tn][r] + hx[grow * 128 + nc], bias[nc]), 0.f);
                outH[grow * 128 + nc] = o;
                acc[tm][tn][r] = o;
            }
        }
        if (WRT) {
#pragma unroll
            for (int p = 0; p < 2; ++p) {
                __syncthreads();
                if (wm == p) {
#pragma unroll
                    for (int tm = 0; tm < 4; ++tm)
#pragma unroll
                    for (int r = 0; r < 4; ++r)
#pragma unroll
                    for (int tn = 0; tn < 4; ++tn)
                        Cl[(tm * 16 + quad * 4 + r) * 129 + wn * 64 + tn * 16 + ln] = acc[tm][tn][r];
                }
                __syncthreads();
                int f = tid >> 1, half = tid & 1;
                ush hb[32] __attribute__((aligned(16)));
                ush mb[32] __attribute__((aligned(16)));
                ush lb[32] __attribute__((aligned(16)));
#pragma unroll
                for (int i = 0; i < 32; ++i)
                    split3(Cl[(half * 32 + i) * 129 + f], hb[i], mb[i], lb[i]);
                long long ob = ((long long)g * 128 + f) * KD + rb * 128 + p * 64 + half * 32;
#pragma unroll
                for (int q = 0; q < 4; ++q) {
                    *(uint4*)(Thi  + ob + q * 8) = *(const uint4*)&hb[q * 8];
                    *(uint4*)(Tmid + ob + q * 8) = *(const uint4*)&mb[q * 8];
                    *(uint4*)(Tlo  + ob + q * 8) = *(const uint4*)&lb[q * 8];
                }
            }
        }
    } else {
#pragma unroll
        for (int tm = 0; tm < 4; ++tm)
#pragma unroll
        for (int r = 0; r < 4; ++r) {
            int ml = wm * 64 + tm * 16 + quad * 4 + r;
            long long grow = rowbase + ml;
            float di = dvec[grow];
            float v = 0.f;
#pragma unroll
            for (int tn = 0; tn < 4; ++tn) {
                int nc = wn * 64 + tn * 16 + ln;
                v += fabsf(hx[grow * 128 + nc] - acc[tm][tn][r] * di);
            }
            v += __shfl_xor(v, 1); v += __shfl_xor(v, 2);
            v += __shfl_xor(v, 4); v += __shfl_xor(v, 8);
            if (ln == 0) sred[wn * 128 + ml] = v;
        }
        __syncthreads();
        if (tid < 128) outS[rowbase + tid] = sred[tid] + sred[128 + tid];
    }
}

// ---------------------------------------------------------------------------
// top-k: bitonic sort of packed keys -> value desc, index asc (jax.lax.top_k)
// ---------------------------------------------------------------------------
template<int NT, int KSEL>
__global__ __launch_bounds__(256) void k_topk(const float* __restrict__ s, int* __restrict__ idx) {
    __shared__ unsigned long long keys[NT];
    int g = blockIdx.x;
    const float* sg = s + g * NT;
    for (int t = threadIdx.x; t < NT; t += 256) {
        unsigned int b = __float_as_uint(sg[t]);
        unsigned int ord = (b & 0x80000000u) ? ~b : (b | 0x80000000u);
        keys[t] = ((unsigned long long)(~ord) << 32) | (unsigned int)t;
    }
    __syncthreads();
    for (int k = 2; k <= NT; k <<= 1) {
        for (int j = k >> 1; j > 0; j >>= 1) {
            for (int i = threadIdx.x; i < NT; i += 256) {
                int l = i ^ j;
                if (l > i) {
                    bool dir = ((i & k) == 0);
                    unsigned long long a = keys[i], b2 = keys[l];
                    bool sw = dir ? (a > b2) : (a < b2);
                    if (sw) { keys[i] = b2; keys[l] = a; }
                }
            }
            __syncthreads();
        }
    }
    for (int t = threadIdx.x; t < KSEL; t += 256)
        idx[g * KSEL + t] = (int)(keys[t] & 0xffffffffu);
}

// ---------------------------------------------------------------------------
// gather pooled rows + attention dot products
// ---------------------------------------------------------------------------
template<int KK>
__global__ __launch_bounds__(256) void k_gather(const float* __restrict__ h, int srcN,
        const int* __restrict__ idx, const float* __restrict__ atts, const float* __restrict__ attd,
        float* __restrict__ xk, float* __restrict__ as_, float* __restrict__ ad_) {
    int wave = threadIdx.x >> 6, lane = threadIdx.x & 63;
    int r = blockIdx.x * 4 + wave;
    int g = r / KK;
    int j = idx[r];
    float2 v = *(const float2*)(h + ((long long)g * srcN + j) * 128 + lane * 2);
    *(float2*)(xk + (long long)r * 128 + lane * 2) = v;
    float2 sv = *(const float2*)(atts + lane * 2);
    float2 dv = *(const float2*)(attd + lane * 2);
    float ps = v.x * sv.x + v.y * sv.y;
    float pd = v.x * dv.x + v.y * dv.y;
    ps = wredsum(ps); pd = wredsum(pd);
    if (lane == 0) { as_[r] = ps; ad_[r] = pd; }
}

// ---------------------------------------------------------------------------
// attention stage-1: softmax(leaky(as_i+ad_j)+adjbf[idx_i,idx_j]);
// writes a1 fp32 + row-major 3-split (A-layout) + deg epilogues
// ---------------------------------------------------------------------------
__global__ __launch_bounds__(256) void k_attn1(const ush* __restrict__ adjbf,
        const int* __restrict__ idx, const float* __restrict__ as_, const float* __restrict__ ad_,
        float* __restrict__ a1, ush* __restrict__ Ahi, ush* __restrict__ Amid, ush* __restrict__ Alo,
        float* __restrict__ dgo, float* __restrict__ dio) {
    __shared__ int   idxL[K1];
    __shared__ float adL[K1];
    __shared__ float rowL[4][N1];
    int g = blockIdx.x / (K1 / 4);
    int wave = threadIdx.x >> 6, lane = threadIdx.x & 63;
    int i = (blockIdx.x % (K1 / 4)) * 4 + wave;
    for (int t = threadIdx.x; t < K1; t += 256) { idxL[t] = idx[g * K1 + t]; adL[t] = ad_[g * K1 + t]; }
    __syncthreads();
    int ri = idxL[i];
    const ush* arow = adjbf + ((long long)g * N1 + ri) * N1;
    for (int c = lane; c < N1; c += 64) rowL[wave][c] = bf2f(arow[c]);
    float asi = as_[g * K1 + i];
    float vals[4];
    float m = -1e30f;
#pragma unroll
    for (int e = 0; e < 4; ++e) {
        int j = e * 64 + lane;
        float x = asi + adL[j];
        x = (x >= 0.f) ? x : 0.2f * x;
        x += rowL[wave][idxL[j]];           // LAMB = 1.0
        vals[e] = x; m = fmaxf(m, x);
    }
    m = wredmax(m);
    float S = 0.f;
#pragma unroll
    for (int e = 0; e < 4; ++e) { vals[e] = expf(vals[e] - m); S += vals[e]; }
    S = wredsum(S);
    float inv = 1.f / S, rs = 0.f;
    float* orow = a1 + ((long long)g * K1 + i) * K1;
#pragma unroll
    for (int e = 0; e < 4; ++e) {
        float p = vals[e] * inv; rs += p;
        orow[e * 64 + lane] = p;
        rowL[wave][e * 64 + lane] = p;      // stage for split write
    }
    rs = wredsum(rs);
    if (lane == 0) { dgo[g * K1 + i] = rsqrtf(rs + 1.f); dio[g * K1 + i] = 1.f / fmaxf(rs, 1.f); }
    // split write: 4 contiguous cols per lane
    long long sb = ((long long)g * K1 + i) * K1 + lane * 4;
    ush hb[4], mb[4], lb[4];
#pragma unroll
    for (int q = 0; q < 4; ++q) split3(rowL[wave][lane * 4 + q], hb[q], mb[q], lb[q]);
    *(ushort4*)(Ahi  + sb) = make_ushort4(hb[0], hb[1], hb[2], hb[3]);
    *(ushort4*)(Amid + sb) = make_ushort4(mb[0], mb[1], mb[2], mb[3]);
    *(ushort4*)(Alo  + sb) = make_ushort4(lb[0], lb[1], lb[2], lb[3]);
}

// ---------------------------------------------------------------------------
// attention stage-2: source adjacency a1 fp32; writes a2 splits only + deg
// ---------------------------------------------------------------------------
__global__ __launch_bounds__(256) void k_attn2(const float* __restrict__ a1,
        const int* __restrict__ idx, const float* __restrict__ as_, const float* __restrict__ ad_,
        ush* __restrict__ Ahi, ush* __restrict__ Amid, ush* __restrict__ Alo,
        float* __restrict__ dgo) {
    __shared__ int   idxL[K2];
    __shared__ float adL[K2];
    __shared__ float rowL[4][K1];
    int g = blockIdx.x / (K2 / 4);
    int wave = threadIdx.x >> 6, lane = threadIdx.x & 63;
    int i = (blockIdx.x % (K2 / 4)) * 4 + wave;
    for (int t = threadIdx.x; t < K2; t += 256) { idxL[t] = idx[g * K2 + t]; adL[t] = ad_[g * K2 + t]; }
    __syncthreads();
    int ri = idxL[i];
    const float* arow = a1 + ((long long)g * K1 + ri) * K1;
    for (int c = lane; c < K1; c += 64) rowL[wave][c] = arow[c];
    float asi = as_[g * K2 + i];
    float vals[2];
    float m = -1e30f;
#pragma unroll
    for (int e = 0; e < 2; ++e) {
        int j = e * 64 + lane;
        float x = asi + adL[j];
        x = (x >= 0.f) ? x : 0.2f * x;
        x += rowL[wave][idxL[j]];
        vals[e] = x; m = fmaxf(m, x);
    }
    m = wredmax(m);
    float S = 0.f;
#pragma unroll
    for (int e = 0; e < 2; ++e) { vals[e] = expf(vals[e] - m); S += vals[e]; }
    S = wredsum(S);
    float inv = 1.f / S, rs = 0.f;
#pragma unroll
    for (int e = 0; e < 2; ++e) {
        float p = vals[e] * inv; rs += p;
        rowL[wave][e * 64 + lane] = p;
    }
    rs = wredsum(rs);
    if (lane == 0) dgo[g * K2 + i] = rsqrtf(rs + 1.f);
    long long sb = ((long long)g * K2 + i) * K2 + lane * 2;
    ush hb[2], mb[2], lb[2];
#pragma unroll
    for (int q = 0; q < 2; ++q) split3(rowL[wave][lane * 2 + q], hb[q], mb[q], lb[q]);
    *(ushort2*)(Ahi  + sb) = make_ushort2(hb[0], hb[1]);
    *(ushort2*)(Amid + sb) = make_ushort2(mb[0], mb[1]);
    *(ushort2*)(Alo  + sb) = make_ushort2(lb[0], lb[1]);
}

// ---------------------------------------------------------------------------
// readout: [max over rows, mean over rows] -> (G, 256); 2-way row split
// ---------------------------------------------------------------------------
template<int KK>
__global__ __launch_bounds__(256) void k_readout(const float* __restrict__ xk, float* __restrict__ xo) {
    __shared__ float sm[2][128], ss[2][128];
    int g = blockIdx.x, t = threadIdx.x;
    int f = t & 127, half = t >> 7;
    const float* p = xk + ((long long)g * KK + half * (KK / 2)) * 128 + f;
    float m = -1e30f, s = 0.f;
    for (int r = 0; r < KK / 2; ++r) { float v = p[r * 128]; m = fmaxf(m, v); s += v; }
    sm[half][f] = m; ss[half][f] = s;
    __syncthreads();
    if (t < 128) {
        xo[g * 256 + t] = fmaxf(sm[0][t], sm[1][t]);
        xo[g * 256 + 128 + t] = (ss[0][t] + ss[1][t]) * (1.0f / KK);
    }
}

// ---------------------------------------------------------------------------
// final MLP + softmax, one block per graph
// ---------------------------------------------------------------------------
__global__ __launch_bounds__(128) void k_mlp(const float* __restrict__ x1, const float* __restrict__ x2,
        const float* __restrict__ x3,
        const float* __restrict__ Wl1, const float* __restrict__ bl1,
        const float* __restrict__ Wl2, const float* __restrict__ bl2,
        const float* __restrict__ Wl3, const float* __restrict__ bl3,
        float* __restrict__ out) {
    __shared__ float z[256], z1[128], z2[64], lg[10];
    int g = blockIdx.x, t = threadIdx.x;
    for (int k = t; k < 256; k += 128)
        z[k] = fmaxf(x1[g * 256 + k], 0.f) + fmaxf(x2[g * 256 + k], 0.f) + fmaxf(x3[g * 256 + k], 0.f);
    __syncthreads();
    {
        float acc = bl1[t];
        for (int k = 0; k < 256; ++k) acc = fmaf(z[k], Wl1[k * 128 + t], acc);
        z1[t] = fmaxf(acc, 0.f);
    }
    __syncthreads();
    if (t < 64) {
        float acc = bl2[t];
        for (int k = 0; k < 128; ++k) acc = fmaf(z1[k], Wl2[k * 64 + t], acc);
        z2[t] = fmaxf(acc, 0.f);
    }
    __syncthreads();
    if (t < 10) {
        float acc = bl3[t];
        for (int k = 0; k < 64; ++k) acc = fmaf(z2[k], Wl3[k * 10 + t], acc);
        lg[t] = acc;
    }
    __syncthreads();
    if (t == 0) {
        float m = -1e30f;
        for (int c = 0; c < 10; ++c) m = fmaxf(m, lg[c]);
        float S = 0.f;
        float e[10];
        for (int c = 0; c < 10; ++c) { e[c] = expf(lg[c] - m); S += e[c]; }
        float inv = 1.f / S;
        for (int c = 0; c < 10; ++c) out[g * 10 + c] = e[c] * inv;
    }
}

// ---------------------------------------------------------------------------
extern "C" void kernel_launch(void* const* d_in, const int* in_sizes, int n_in,
                              void* d_out, int out_size, void* d_ws, size_t ws_size,
                              hipStream_t stream) {
    const float* x     = (const float*)d_in[0];
    const float* adj   = (const float*)d_in[1];
    const float* W1    = (const float*)d_in[2];
    const float* b1    = (const float*)d_in[3];
    const float* W2    = (const float*)d_in[4];
    const float* b2    = (const float*)d_in[5];
    const float* W3    = (const float*)d_in[6];
    const float* b3    = (const float*)d_in[7];
    const float* att1s = (const float*)d_in[8];
    const float* att1d = (const float*)d_in[9];
    const float* att2s = (const float*)d_in[10];
    const float* att2d = (const float*)d_in[11];
    const float* Wl1   = (const float*)d_in[12];
    const float* bl1   = (const float*)d_in[13];
    const float* Wl2   = (const float*)d_in[14];
    const float* bl2   = (const float*)d_in[15];
    const float* Wl3   = (const float*)d_in[16];
    const float* bl3   = (const float*)d_in[17];
    float* out = (float*)d_out;

    char* ws = (char*)d_ws;
    // ---- workspace (~438 MB of the 512 MiB ws; no cross-stage aliasing) ----
    ush*   adjbf  = (ush*)  (ws + 0);             // 67,108,864
    ush*   T1hi   = (ush*)  (ws + 67108864);      // dxw1^T splits, 3x16 MB
    ush*   T1mid  = (ush*)  (ws + 83886080);
    ush*   T1lo   = (ush*)  (ws + 100663296);
    ush*   T2hi   = (ush*)  (ws + 117440512);     // h1^T splits
    ush*   T2mid  = (ush*)  (ws + 134217728);
    ush*   T2lo   = (ush*)  (ws + 150994944);
    float* dxw1   = (float*)(ws + 167772160);     // 33.5 MB; h1 in-place
    float* h1     = dxw1;
    float* a1     = (float*)(ws + 201326592);     // 33.5 MB
    ush*   A1hi   = (ush*)  (ws + 234881024);     // a1 splits, 3x16 MB
    ush*   A1mid  = (ush*)  (ws + 251658240);
    ush*   A1lo   = (ush*)  (ws + 268435456);
    ush*   Y2hi   = (ush*)  (ws + 285212672);     // dxw2^T splits, 3x8 MB
    ush*   Y2mid  = (ush*)  (ws + 293601280);
    ush*   Y2lo   = (ush*)  (ws + 301989888);
    ush*   H2hi   = (ush*)  (ws + 310378496);     // h2^T splits, 3x8 MB
    ush*   H2mid  = (ush*)  (ws + 318767104);
    ush*   H2lo   = (ush*)  (ws + 327155712);
    float* dxw2   = (float*)(ws + 335544320);     // 16.8 MB
    float* h2     = (float*)(ws + 352321536);     // 16.8 MB
    float* xk1    = (float*)(ws + 369098752);     // 16.8 MB
    float* xk2    = (float*)(ws + 385875968);     // 8.4 MB
    ush*   A2hi   = (ush*)  (ws + 394264576);     // a2 splits, 3x4 MB
    ush*   A2mid  = (ush*)  (ws + 398458880);
    ush*   A2lo   = (ush*)  (ws + 402653184);
    ush*   Y3hi   = (ush*)  (ws + 406847488);     // dxw3^T splits, 3x4 MB
    ush*   Y3mid  = (ush*)  (ws + 411041792);
    ush*   Y3lo   = (ush*)  (ws + 415236096);
    float* dxw3   = (float*)(ws + 419430400);     // 8.4 MB
    float* h3     = (float*)(ws + 427819008);     // 8.4 MB
    float* s1     = (float*)(ws + 436207616);
    int*   idx1   = (int*)  (ws + 436469760);
    float* as1    = (float*)(ws + 436600832);
    float* ad1    = (float*)(ws + 436731904);
    float* dinv_g1= (float*)(ws + 436862976);
    float* dinv_i1= (float*)(ws + 437125120);
    float* dinv_g2= (float*)(ws + 437387264);
    float* dinv_i2= (float*)(ws + 437518336);
    float* x1r    = (float*)(ws + 437649408);
    float* s2     = (float*)(ws + 437780480);
    int*   idx2   = (int*)  (ws + 437911552);
    float* as2    = (float*)(ws + 437977088);
    float* ad2    = (float*)(ws + 438042624);
    float* dinv_g3= (float*)(ws + 438108160);
    float* x2r    = (float*)(ws + 438173696);
    float* x3r    = (float*)(ws + 438304768);

    // stage 1: full graph (N=512)
    k_prep<<<Gg * N1 / 4, 256, 0, stream>>>(adj, dinv_g1, dinv_i1, adjbf);
    k_gemm_rwt<N1><<<Gg * N1 / 64, 256, 0, stream>>>(x, W1, dxw1, dinv_g1, T1hi, T1mid, T1lo);
    k_aggmm2<0, true><<<Gg * 4, 256, 0, stream>>>(adjbf, T1hi, T1mid, T1lo, dinv_g1, dxw1, b1,
                                                  h1, nullptr, T2hi, T2mid, T2lo);
    k_aggmm2<1, false><<<Gg * 4, 256, 0, stream>>>(adjbf, T2hi, T2mid, T2lo, dinv_i1, h1, nullptr,
                                                   nullptr, s1, nullptr, nullptr, nullptr);
    k_topk<N1, K1><<<Gg, 256, 0, stream>>>(s1, idx1);
    k_gather<K1><<<Gg * K1 / 4, 256, 0, stream>>>(h1, N1, idx1, att1s, att1d, xk1, as1, ad1);
    k_readout<K1><<<Gg, 256, 0, stream>>>(xk1, x1r);
    k_attn1<<<Gg * K1 / 4, 256, 0, stream>>>(adjbf, idx1, as1, ad1, a1, A1hi, A1mid, A1lo,
                                             dinv_g2, dinv_i2);

    // stage 2: pooled graph (K1=256)
    k_gemm_rwt<K1><<<Gg * K1 / 64, 256, 0, stream>>>(xk1, W2, dxw2, dinv_g2, Y2hi, Y2mid, Y2lo);
    k_aggp<K1, 0, true><<<Gg * 2, 256, 0, stream>>>(A1hi, A1mid, A1lo, Y2hi, Y2mid, Y2lo,
                                                    dinv_g2, dxw2, b2, h2, nullptr, H2hi, H2mid, H2lo);
    k_aggp<K1, 1, false><<<Gg * 2, 256, 0, stream>>>(A1hi, A1mid, A1lo, H2hi, H2mid, H2lo,
                                                     dinv_i2, h2, nullptr, nullptr, s2,
                                                     nullptr, nullptr, nullptr);
    k_topk<K1, K2><<<Gg, 256, 0, stream>>>(s2, idx2);
    k_gather<K2><<<Gg * K2 / 4, 256, 0, stream>>>(h2, K1, idx2, att2s, att2d, xk2, as2, ad2);
    k_readout<K2><<<Gg, 256, 0, stream>>>(xk2, x2r);
    k_attn2<<<Gg * K2 / 4, 256, 0, stream>>>(a1, idx2, as2, ad2, A2hi, A2mid, A2lo, dinv_g3);

    // stage 3: pooled graph (K2=128)
    k_gemm_rwt<K2><<<Gg * K2 / 64, 256, 0, stream>>>(xk2, W3, dxw3, dinv_g3, Y3hi, Y3mid, Y3lo);
    k_aggp<K2, 0, false><<<Gg, 256, 0, stream>>>(A2hi, A2mid, A2lo, Y3hi, Y3mid, Y3lo,
                                                 dinv_g3, dxw3, b3, h3, nullptr,
                                                 nullptr, nullptr, nullptr);
    k_readout<K2><<<Gg, 256, 0, stream>>>(h3, x3r);

    // final MLP
    k_mlp<<<Gg, 128, 0, stream>>>(x1r, x2r, x3r, Wl1, bl1, Wl2, bl2, Wl3, bl3, out);
}